// Round 1
// baseline (792.346 us; speedup 1.0000x reference)
//
#include <hip/hip_runtime.h>
#include <math.h>

#define BB 8
#define CC 256
#define NN 4096
#define DD 32
#define NK 1024
#define SCALE 0.1767766952966369f   // 1/sqrt(32)

// workspace offsets (in floats)
#define OFF_XKV  0u          // [B][C][NK]        2,097,152
#define OFF_Q    2097152u    // [B][N][D]         1,048,576
#define OFF_KT   3145728u    // [B][NK][D]          262,144
#define OFF_VOT  3407872u    // [B][NK][C]        2,097,152
#define OFF_WVOT 5505024u    // [C][C]  (c-major)    65,536
#define OFF_WQT  5570560u    // [C][D]                8,192
#define OFF_WKT  5578752u    // [C][D]                8,192
// total 5,586,944 floats = 22.35 MB

union F4 { float4 v; float f[4]; };

// ---------------- avgpool 2x2: x[B,C,64,64] -> xkv[B,C,1024] ----------------
__global__ void pool_kernel(const float* __restrict__ x, float* __restrict__ xkv) {
    int id = blockIdx.x * 256 + threadIdx.x;      // B*C*NK = 2,097,152
    int m  = id & (NK - 1);
    int bc = id >> 10;
    int hk = m >> 5, wk = m & 31;
    const float* p = x + (size_t)bc * 4096 + hk * 128 + wk * 2;
    xkv[id] = 0.25f * (p[0] + p[1] + p[64] + p[65]);
}

// ------------- weight prep: wvoT[c][o] = (wo@wv)[o][c]; transpose wq,wk -----
__global__ void wprep_kernel(const float* __restrict__ wq, const float* __restrict__ wk,
                             const float* __restrict__ wv, const float* __restrict__ wo,
                             float* __restrict__ wqT, float* __restrict__ wkT,
                             float* __restrict__ wvoT) {
    int c = blockIdx.x;           // 0..255
    int o = threadIdx.x;          // 0..255
    float acc = 0.f;
    for (int j = 0; j < CC; ++j)
        acc += wo[o * CC + j] * wv[j * CC + c];   // wv read is wave-uniform (scalar)
    wvoT[c * CC + o] = acc;
    int id = blockIdx.x * 256 + threadIdx.x;
    if (id < CC * DD) {
        int dd = id & 31, cc2 = id >> 5;
        wqT[cc2 * DD + dd] = wq[dd * CC + cc2];
        wkT[cc2 * DD + dd] = wk[dd * CC + cc2];
    }
}

// ---------------- q projection: q[b][n][d] = sum_c wq[d][c] x[b][c][n] ------
__launch_bounds__(256)
__global__ void q_kernel(const float* __restrict__ x, const float* __restrict__ wqT,
                         float* __restrict__ q) {
    int b = blockIdx.x >> 4;                        // 16 blocks per batch
    int n = ((blockIdx.x & 15) << 8) + threadIdx.x;
    const float* xb = x + (size_t)b * CC * NN + n;
    float acc[DD];
#pragma unroll
    for (int i = 0; i < DD; ++i) acc[i] = 0.f;
#pragma unroll 4
    for (int c = 0; c < CC; ++c) {
        float xv = xb[(size_t)c * NN];
#pragma unroll
        for (int i = 0; i < DD; ++i) acc[i] += wqT[c * DD + i] * xv;  // uniform -> s_load
    }
    float* qp = q + ((size_t)b * NN + n) * DD;
#pragma unroll
    for (int i = 0; i < DD; i += 4)
        *(float4*)(qp + i) = make_float4(acc[i], acc[i+1], acc[i+2], acc[i+3]);
}

// ---------------- k projection: kT[b][m][d] = sum_c wk[d][c] xkv[b][c][m] ---
__launch_bounds__(256)
__global__ void k_kernel(const float* __restrict__ xkv, const float* __restrict__ wkT,
                         float* __restrict__ kT) {
    int id = blockIdx.x * 256 + threadIdx.x;      // B*NK = 8192
    int b = id >> 10, m = id & (NK - 1);
    const float* xb = xkv + (size_t)b * CC * NK + m;
    float acc[DD];
#pragma unroll
    for (int i = 0; i < DD; ++i) acc[i] = 0.f;
#pragma unroll 4
    for (int c = 0; c < CC; ++c) {
        float xv = xb[(size_t)c * NK];
#pragma unroll
        for (int i = 0; i < DD; ++i) acc[i] += wkT[c * DD + i] * xv;
    }
    float* kp = kT + ((size_t)b * NK + m) * DD;
#pragma unroll
    for (int i = 0; i < DD; i += 4)
        *(float4*)(kp + i) = make_float4(acc[i], acc[i+1], acc[i+2], acc[i+3]);
}

// ------------- vo projection: voT[b][m][o] = sum_c wvoT[c][o] xkv[b][c][m] --
__launch_bounds__(256)
__global__ void v_kernel(const float* __restrict__ xkv, const float* __restrict__ wvoT,
                         float* __restrict__ voT) {
    __shared__ __align__(16) float xlds[CC * 32];   // [c][mm] 32 KB
    int b  = blockIdx.x >> 5;
    int m0 = (blockIdx.x & 31) << 5;
    int t  = threadIdx.x;
#pragma unroll
    for (int i = 0; i < 32; ++i) {
        int idx = t + 256 * i;                      // 8192
        int c = idx >> 5, mm = idx & 31;
        xlds[idx] = xkv[((size_t)b * CC + c) * NK + m0 + mm];
    }
    __syncthreads();
    int ml = t & 31, og = t >> 5;                   // og 0..7 -> o = og*32..+31
    float acc[32];
#pragma unroll
    for (int i = 0; i < 32; ++i) acc[i] = 0.f;
#pragma unroll 2
    for (int c = 0; c < CC; ++c) {
        float xv = xlds[c * 32 + ml];
        const float4* wp = (const float4*)(wvoT + c * CC + og * 32);
#pragma unroll
        for (int k4 = 0; k4 < 8; ++k4) {
            F4 w; w.v = wp[k4];
            acc[k4*4+0] += w.f[0] * xv;
            acc[k4*4+1] += w.f[1] * xv;
            acc[k4*4+2] += w.f[2] * xv;
            acc[k4*4+3] += w.f[3] * xv;
        }
    }
    float* out = voT + ((size_t)b * NK + m0 + ml) * CC + og * 32;
#pragma unroll
    for (int k4 = 0; k4 < 8; ++k4)
        *(float4*)(out + k4 * 4) = make_float4(acc[k4*4], acc[k4*4+1], acc[k4*4+2], acc[k4*4+3]);
}

// ---------------- fused attention + epilogue --------------------------------
// block: 256 threads, handles (batch b, 16 query rows). grid = 8*256 = 2048.
__launch_bounds__(256)
__global__ void attn_kernel(const float* __restrict__ q, const float* __restrict__ kT,
                            const float* __restrict__ voT, const float* __restrict__ x,
                            const float* __restrict__ gamma, float* __restrict__ out) {
    __shared__ __align__(16) float S[16 * 1024];    // scores/P; later aliased as OT[256][17]
    __shared__ __align__(16) float q_lds[16 * 32];
    __shared__ float l_lds[16];

    int blk  = blockIdx.x;
    int b    = blk & 7;          // XCD-pin: same batch -> same XCD (round-robin)
    int tile = blk >> 3;         // 0..255
    int n0   = tile << 4;
    int t    = threadIdx.x;

    // load q tile [16][32]
    if (t < 128)
        *(float4*)(q_lds + t * 4) = *(const float4*)(q + ((size_t)(b * NN + n0)) * DD + t * 4);
    __syncthreads();

    // ---- phase B: scores S[n][m] = scale * q[n]·kT[m], 2 m per thread/pass --
    const float* kTb = kT + (size_t)b * NK * DD;
    for (int pass = 0; pass < 2; ++pass) {
        int m1 = t + pass * 512;          // m1 and m1+256
        float ka[DD], kb[DD];
        const float4* k1 = (const float4*)(kTb + (size_t)m1 * DD);
        const float4* k2 = (const float4*)(kTb + (size_t)(m1 + 256) * DD);
#pragma unroll
        for (int i = 0; i < 8; ++i) {
            F4 a; a.v = k1[i];
            F4 c; c.v = k2[i];
            ka[i*4+0]=a.f[0]; ka[i*4+1]=a.f[1]; ka[i*4+2]=a.f[2]; ka[i*4+3]=a.f[3];
            kb[i*4+0]=c.f[0]; kb[i*4+1]=c.f[1]; kb[i*4+2]=c.f[2]; kb[i*4+3]=c.f[3];
        }
#pragma unroll
        for (int n = 0; n < 16; ++n) {
            float s1 = 0.f, s2 = 0.f;
#pragma unroll
            for (int i = 0; i < 8; ++i) {
                F4 qv; qv.v = *(const float4*)(q_lds + n * DD + i * 4);
                s1 += qv.f[0]*ka[i*4+0] + qv.f[1]*ka[i*4+1] + qv.f[2]*ka[i*4+2] + qv.f[3]*ka[i*4+3];
                s2 += qv.f[0]*kb[i*4+0] + qv.f[1]*kb[i*4+1] + qv.f[2]*kb[i*4+2] + qv.f[3]*kb[i*4+3];
            }
            S[n * NK + m1]       = s1 * SCALE;
            S[n * NK + m1 + 256] = s2 * SCALE;
        }
    }
    __syncthreads();

    // ---- phase C: softmax (unnormalized exp kept; row sums in l_lds) --------
    int wave = t >> 6, lane = t & 63;
#pragma unroll
    for (int r = 0; r < 4; ++r) {
        int n = wave * 4 + r;
        float mx = -1e30f;
#pragma unroll
        for (int j = 0; j < 16; ++j) mx = fmaxf(mx, S[n * NK + lane + 64 * j]);
#pragma unroll
        for (int off = 32; off; off >>= 1) mx = fmaxf(mx, __shfl_xor(mx, off));
        float sum = 0.f;
#pragma unroll
        for (int j = 0; j < 16; ++j) {
            float e = __expf(S[n * NK + lane + 64 * j] - mx);
            S[n * NK + lane + 64 * j] = e;
            sum += e;
        }
#pragma unroll
        for (int off = 32; off; off >>= 1) sum += __shfl_xor(sum, off);
        if (lane == 0) l_lds[n] = sum;
    }
    __syncthreads();

    // ---- phase D: PV.  thread -> (og = o-group of 8, ng = n-pair) -----------
    int og = t & 31, ng = t >> 5;
    const float* voTb = voT + (size_t)b * NK * CC + og * 8;
    float acc0[8], acc1[8];
#pragma unroll
    for (int i = 0; i < 8; ++i) { acc0[i] = 0.f; acc1[i] = 0.f; }
    const float* Sr0 = S + (ng * 2) * NK;
    const float* Sr1 = Sr0 + NK;
#pragma unroll 2
    for (int m4 = 0; m4 < NK; m4 += 4) {
        F4 pa; pa.v = *(const float4*)(Sr0 + m4);
        F4 pb; pb.v = *(const float4*)(Sr1 + m4);
#pragma unroll
        for (int mm = 0; mm < 4; ++mm) {
            F4 v0; v0.v = *(const float4*)(voTb + (size_t)(m4 + mm) * CC);
            F4 v1; v1.v = *(const float4*)(voTb + (size_t)(m4 + mm) * CC + 4);
            float p0 = pa.f[mm], p1 = pb.f[mm];
#pragma unroll
            for (int k = 0; k < 4; ++k) {
                acc0[k]     += p0 * v0.f[k];
                acc0[4 + k] += p0 * v1.f[k];
                acc1[k]     += p1 * v0.f[k];
                acc1[4 + k] += p1 * v1.f[k];
            }
        }
    }
    __syncthreads();   // all P reads done -> reuse S as OT[256][17]

    float* OT = S;
    float linv0 = 1.0f / l_lds[ng * 2];
    float linv1 = 1.0f / l_lds[ng * 2 + 1];
#pragma unroll
    for (int k = 0; k < 8; ++k) {
        OT[(og * 8 + k) * 17 + ng * 2]     = acc0[k] * linv0;
        OT[(og * 8 + k) * 17 + ng * 2 + 1] = acc1[k] * linv1;
    }
    __syncthreads();

    // ---- epilogue: out[b][o][n0..n0+15] = x + gamma*O, o = t ----------------
    float g = gamma[0];
    const float* xr = x   + ((size_t)b * CC + t) * NN + n0;
    float*       op = out + ((size_t)b * CC + t) * NN + n0;
#pragma unroll
    for (int j = 0; j < 4; ++j) {
        float4 xv = *(const float4*)(xr + j * 4);
        float4 ov;
        ov.x = xv.x + g * OT[t * 17 + j * 4 + 0];
        ov.y = xv.y + g * OT[t * 17 + j * 4 + 1];
        ov.z = xv.z + g * OT[t * 17 + j * 4 + 2];
        ov.w = xv.w + g * OT[t * 17 + j * 4 + 3];
        *(float4*)(op + j * 4) = ov;
    }
}

extern "C" void kernel_launch(void* const* d_in, const int* in_sizes, int n_in,
                              void* d_out, int out_size, void* d_ws, size_t ws_size,
                              hipStream_t stream) {
    const float* x     = (const float*)d_in[0];
    const float* wq    = (const float*)d_in[1];
    const float* wk    = (const float*)d_in[2];
    const float* wv    = (const float*)d_in[3];
    const float* wo    = (const float*)d_in[4];
    const float* gamma = (const float*)d_in[5];
    float* out = (float*)d_out;
    float* ws  = (float*)d_ws;

    float* xkv  = ws + OFF_XKV;
    float* q    = ws + OFF_Q;
    float* kT   = ws + OFF_KT;
    float* voT  = ws + OFF_VOT;
    float* wvoT = ws + OFF_WVOT;
    float* wqT  = ws + OFF_WQT;
    float* wkT  = ws + OFF_WKT;

    pool_kernel <<<dim3((BB*CC*NK)/256), dim3(256), 0, stream>>>(x, xkv);
    wprep_kernel<<<dim3(256),            dim3(256), 0, stream>>>(wq, wk, wv, wo, wqT, wkT, wvoT);
    q_kernel    <<<dim3((BB*NN)/256),    dim3(256), 0, stream>>>(x, wqT, q);
    k_kernel    <<<dim3((BB*NK)/256),    dim3(256), 0, stream>>>(xkv, wkT, kT);
    v_kernel    <<<dim3(BB*32),          dim3(256), 0, stream>>>(xkv, wvoT, voT);
    attn_kernel <<<dim3(BB*256),         dim3(256), 0, stream>>>(q, kT, voT, x, gamma, out);
}

// Round 2
// 302.673 us; speedup vs baseline: 2.6178x; 2.6178x over previous
//
#include <hip/hip_runtime.h>
#include <math.h>

#define BB 8
#define CC 256
#define NN 4096
#define DD 32
#define NK 1024

typedef unsigned short u16;
typedef unsigned int   u32;
typedef __attribute__((ext_vector_type(8))) short bf16x8;
typedef __attribute__((ext_vector_type(4))) float f32x4;

// workspace offsets (in floats)
#define OFF_XKV   0u         // [B][C][NK] fp32     2,097,152
#define OFF_WVOT  2097152u   // [C][C] fp32            65,536
#define OFF_WQT   2162688u   // [C][D] fp32             8,192
#define OFF_WKT   2170880u   // [C][D] fp32             8,192
#define OFF_QBF   2179072u   // [B][N][D] bf16  (524,288 f)
#define OFF_KBF   2703360u   // [B][NK][D] bf16 (131,072 f)
#define OFF_VOBF  2834432u   // [B][C][NK] bf16 (1,048,576 f)
// total 3,883,008 floats = 15.5 MB

__device__ __forceinline__ u16 f2bf(float f) {
    u32 u = __float_as_uint(f);
    u += 0x7FFFu + ((u >> 16) & 1u);      // round-to-nearest-even
    return (u16)(u >> 16);
}

// ---------------- avgpool 2x2: x[B,C,64,64] -> xkv[B,C,1024] ----------------
__global__ void pool_kernel(const float* __restrict__ x, float* __restrict__ xkv) {
    int id = blockIdx.x * 256 + threadIdx.x;
    int m  = id & (NK - 1);
    int bc = id >> 10;
    int hk = m >> 5, wk = m & 31;
    const float* p = x + (size_t)bc * 4096 + hk * 128 + wk * 2;
    xkv[id] = 0.25f * (p[0] + p[1] + p[64] + p[65]);
}

// ------------- weight prep: wvoT[c][o] = (wo@wv)[o][c]; transpose wq,wk -----
__global__ void wprep_kernel(const float* __restrict__ wq, const float* __restrict__ wk,
                             const float* __restrict__ wv, const float* __restrict__ wo,
                             float* __restrict__ wqT, float* __restrict__ wkT,
                             float* __restrict__ wvoT) {
    int c = blockIdx.x;
    int o = threadIdx.x;
    float acc = 0.f;
    for (int j = 0; j < CC; ++j)
        acc += wo[o * CC + j] * wv[j * CC + c];
    wvoT[c * CC + o] = acc;
    int id = blockIdx.x * 256 + threadIdx.x;
    if (id < CC * DD) {
        int dd = id & 31, cc2 = id >> 5;
        wqT[cc2 * DD + dd] = wq[dd * CC + cc2];
        wkT[cc2 * DD + dd] = wk[dd * CC + cc2];
    }
}

// ------- q projection -> bf16, scale*log2e folded: q[b][n][d] ---------------
__launch_bounds__(256)
__global__ void q_kernel(const float* __restrict__ x, const float* __restrict__ wqT,
                         u16* __restrict__ qbf) {
    int b = blockIdx.x >> 4;
    int n = ((blockIdx.x & 15) << 8) + threadIdx.x;
    const float* xb = x + (size_t)b * CC * NN + n;
    float acc[DD];
#pragma unroll
    for (int i = 0; i < DD; ++i) acc[i] = 0.f;
#pragma unroll 4
    for (int c = 0; c < CC; ++c) {
        float xv = xb[(size_t)c * NN];
#pragma unroll
        for (int i = 0; i < DD; ++i) acc[i] += wqT[c * DD + i] * xv;
    }
    const float QS = 0.17677669529663687f * 1.4426950408889634f; // 1/sqrt(32)*log2(e)
    u16* qp = qbf + ((size_t)b * NN + n) * DD;
    u32 u[16];
#pragma unroll
    for (int i = 0; i < 16; ++i)
        u[i] = (u32)f2bf(acc[2*i] * QS) | ((u32)f2bf(acc[2*i+1] * QS) << 16);
#pragma unroll
    for (int i = 0; i < 4; ++i)
        *(uint4*)(qp + i * 8) = make_uint4(u[4*i], u[4*i+1], u[4*i+2], u[4*i+3]);
}

// ------- k projection -> bf16: kT[b][m][d] ----------------------------------
__launch_bounds__(256)
__global__ void k_kernel(const float* __restrict__ xkv, const float* __restrict__ wkT,
                         u16* __restrict__ kbf) {
    int id = blockIdx.x * 256 + threadIdx.x;      // B*NK
    int b = id >> 10, m = id & (NK - 1);
    const float* xb = xkv + (size_t)b * CC * NK + m;
    float acc[DD];
#pragma unroll
    for (int i = 0; i < DD; ++i) acc[i] = 0.f;
#pragma unroll 4
    for (int c = 0; c < CC; ++c) {
        float xv = xb[(size_t)c * NK];
#pragma unroll
        for (int i = 0; i < DD; ++i) acc[i] += wkT[c * DD + i] * xv;
    }
    u16* kp = kbf + ((size_t)b * NK + m) * DD;
    u32 u[16];
#pragma unroll
    for (int i = 0; i < 16; ++i)
        u[i] = (u32)f2bf(acc[2*i]) | ((u32)f2bf(acc[2*i+1]) << 16);
#pragma unroll
    for (int i = 0; i < 4; ++i)
        *(uint4*)(kp + i * 8) = make_uint4(u[4*i], u[4*i+1], u[4*i+2], u[4*i+3]);
}

// ------- vo projection -> bf16 [b][o][m]: vo = (wo@wv) @ xkv ----------------
__launch_bounds__(256)
__global__ void v_kernel(const float* __restrict__ xkv, const float* __restrict__ wvoT,
                         u16* __restrict__ vobf) {
    __shared__ __align__(16) float xlds[CC * 32];
    int b  = blockIdx.x >> 5;
    int m0 = (blockIdx.x & 31) << 5;
    int t  = threadIdx.x;
#pragma unroll
    for (int i = 0; i < 32; ++i) {
        int idx = t + 256 * i;
        int c = idx >> 5, mm = idx & 31;
        xlds[idx] = xkv[((size_t)b * CC + c) * NK + m0 + mm];
    }
    __syncthreads();
    int ml = t & 31, og = t >> 5;
    float acc[32];
#pragma unroll
    for (int i = 0; i < 32; ++i) acc[i] = 0.f;
#pragma unroll 2
    for (int c = 0; c < CC; ++c) {
        float xv = xlds[c * 32 + ml];
        const float4* wp = (const float4*)(wvoT + c * CC + og * 32);
#pragma unroll
        for (int k4 = 0; k4 < 8; ++k4) {
            float4 w = wp[k4];
            acc[k4*4+0] += w.x * xv;
            acc[k4*4+1] += w.y * xv;
            acc[k4*4+2] += w.z * xv;
            acc[k4*4+3] += w.w * xv;
        }
    }
    u16* vout = vobf + ((size_t)b * CC + og * 32) * NK + m0 + ml;
#pragma unroll
    for (int i = 0; i < 32; ++i)
        vout[(size_t)i * NK] = f2bf(acc[i]);
}

// ---------------- fused flash attention (MFMA) + epilogue -------------------
// block: 256 threads = 4 waves; 64 q-rows/block (16/wave); grid = 8 * 64.
__launch_bounds__(256)
__global__ void attn_kernel(const u16* __restrict__ qbf, const u16* __restrict__ kbf,
                            const u16* __restrict__ vobf, const float* __restrict__ x,
                            const float* __restrict__ gamma, float* __restrict__ out) {
    __shared__ __align__(16) u16  vo_lds[2][256 * 40];  // [o][32m] pad-40, dbuf (40 KB)
    __shared__ __align__(16) u16  p_lds[4][16 * 40];    // per-wave P tile [16n][32m] pad-40
    __shared__ __align__(16) float rs_lds[4][16];

    const int t  = threadIdx.x;
    const int w  = t >> 6, l = t & 63;
    const int l15 = l & 15, lg = l >> 4;
    const int b  = blockIdx.x & 7;               // batch -> XCD pin
    const int n0 = (blockIdx.x >> 3) << 6;       // 64-row tile

    const u16* qb = qbf  + (size_t)b * NN * DD;
    const u16* kb = kbf  + (size_t)b * NK * DD;
    const u16* vb = vobf + (size_t)b * CC * NK;

    // Q fragment (B operand): col n = n0 + w*16 + l15, k = lg*8..+7
    bf16x8 qf = *(const bf16x8*)(qb + (size_t)(n0 + w * 16 + l15) * DD + lg * 8);

    f32x4 acc[16];
    const f32x4 fzero = {0.f, 0.f, 0.f, 0.f};
#pragma unroll
    for (int i = 0; i < 16; ++i) acc[i] = fzero;
    float rs = 0.f;

    // VO staging: thread t covers rows srow, srow+64, ... ; 16B slot sq
    const int srow = t >> 2;
    const int sq   = t & 3;
    uint4 sreg[4];

    // prologue: stage chunk 0 into buf 0
#pragma unroll
    for (int j = 0; j < 4; ++j)
        sreg[j] = *(const uint4*)(vb + (size_t)(srow + j * 64) * NK + sq * 8);
#pragma unroll
    for (int j = 0; j < 4; ++j)
        *(uint4*)&vo_lds[0][(srow + j * 64) * 40 + sq * 8] = sreg[j];
    __syncthreads();

    for (int i = 0; i < 32; ++i) {
        const int buf = i & 1;
        const int mt  = i * 32;
        if (i < 31) {
#pragma unroll
            for (int j = 0; j < 4; ++j)
                sreg[j] = *(const uint4*)(vb + (size_t)(srow + j * 64) * NK + (mt + 32) + sq * 8);
        }
        // ---- S^T = K * Q^T : lane holds n=l15, m = mt + lg*4 + r (+16) ------
        bf16x8 kf0 = *(const bf16x8*)(kb + (size_t)(mt + l15) * DD + lg * 8);
        bf16x8 kf1 = *(const bf16x8*)(kb + (size_t)(mt + 16 + l15) * DD + lg * 8);
        f32x4 c0 = __builtin_amdgcn_mfma_f32_16x16x32_bf16(kf0, qf, fzero, 0, 0, 0);
        f32x4 c1 = __builtin_amdgcn_mfma_f32_16x16x32_bf16(kf1, qf, fzero, 0, 0, 0);
        // ---- exp2 (scale*log2e pre-folded into q); accumulate row sums ------
        float e0 = __builtin_amdgcn_exp2f(c0[0]);
        float e1 = __builtin_amdgcn_exp2f(c0[1]);
        float e2 = __builtin_amdgcn_exp2f(c0[2]);
        float e3 = __builtin_amdgcn_exp2f(c0[3]);
        float e4 = __builtin_amdgcn_exp2f(c1[0]);
        float e5 = __builtin_amdgcn_exp2f(c1[1]);
        float e6 = __builtin_amdgcn_exp2f(c1[2]);
        float e7 = __builtin_amdgcn_exp2f(c1[3]);
        rs += (e0 + e1 + e2 + e3) + (e4 + e5 + e6 + e7);
        uint2 pw0, pw1;
        pw0.x = (u32)f2bf(e0) | ((u32)f2bf(e1) << 16);
        pw0.y = (u32)f2bf(e2) | ((u32)f2bf(e3) << 16);
        pw1.x = (u32)f2bf(e4) | ((u32)f2bf(e5) << 16);
        pw1.y = (u32)f2bf(e6) | ((u32)f2bf(e7) << 16);
        u16* pw = &p_lds[w][l15 * 40 + lg * 4];
        *(uint2*)pw        = pw0;   // m-local lg*4..+3
        *(uint2*)(pw + 16) = pw1;   // m-local 16+lg*4..+3
        // ---- P A-fragment: row n=l15, k m = lg*8..+7 ------------------------
        bf16x8 pa = *(const bf16x8*)&p_lds[w][l15 * 40 + lg * 8];
        // ---- PV: 16 o-tiles -------------------------------------------------
#pragma unroll
        for (int ot = 0; ot < 16; ++ot) {
            bf16x8 bfr = *(const bf16x8*)&vo_lds[buf][(ot * 16 + l15) * 40 + lg * 8];
            acc[ot] = __builtin_amdgcn_mfma_f32_16x16x32_bf16(pa, bfr, acc[ot], 0, 0, 0);
        }
        if (i < 31) {
#pragma unroll
            for (int j = 0; j < 4; ++j)
                *(uint4*)&vo_lds[buf ^ 1][(srow + j * 64) * 40 + sq * 8] = sreg[j];
            __syncthreads();
        }
    }

    // ---- row-sum reduce across the 4 lane-groups sharing n = l15 -----------
    rs += __shfl_xor(rs, 16);
    rs += __shfl_xor(rs, 32);
    if (l < 16) rs_lds[w][l] = rs;
    float4 rv = *(const float4*)&rs_lds[w][lg * 4];
    float g = gamma[0];
    float fa0 = g / rv.x, fa1 = g / rv.y, fa2 = g / rv.z, fa3 = g / rv.w;

    // ---- epilogue: out[b][o][n] = x + gamma * O/l ---------------------------
    const size_t nb = (size_t)n0 + w * 16 + lg * 4;
#pragma unroll
    for (int ot = 0; ot < 16; ++ot) {
        size_t base = ((size_t)(b * CC + ot * 16 + l15)) * NN + nb;
        float4 xv = *(const float4*)(x + base);
        float4 ov;
        ov.x = xv.x + acc[ot][0] * fa0;
        ov.y = xv.y + acc[ot][1] * fa1;
        ov.z = xv.z + acc[ot][2] * fa2;
        ov.w = xv.w + acc[ot][3] * fa3;
        *(float4*)(out + base) = ov;
    }
}

extern "C" void kernel_launch(void* const* d_in, const int* in_sizes, int n_in,
                              void* d_out, int out_size, void* d_ws, size_t ws_size,
                              hipStream_t stream) {
    const float* x     = (const float*)d_in[0];
    const float* wq    = (const float*)d_in[1];
    const float* wk    = (const float*)d_in[2];
    const float* wv    = (const float*)d_in[3];
    const float* wo    = (const float*)d_in[4];
    const float* gamma = (const float*)d_in[5];
    float* out = (float*)d_out;
    float* ws  = (float*)d_ws;

    float* xkv  = ws + OFF_XKV;
    float* wvoT = ws + OFF_WVOT;
    float* wqT  = ws + OFF_WQT;
    float* wkT  = ws + OFF_WKT;
    u16*   qbf  = (u16*)(ws + OFF_QBF);
    u16*   kbf  = (u16*)(ws + OFF_KBF);
    u16*   vobf = (u16*)(ws + OFF_VOBF);

    pool_kernel <<<dim3((BB*CC*NK)/256), dim3(256), 0, stream>>>(x, xkv);
    wprep_kernel<<<dim3(256),            dim3(256), 0, stream>>>(wq, wk, wv, wo, wqT, wkT, wvoT);
    q_kernel    <<<dim3((BB*NN)/256),    dim3(256), 0, stream>>>(x, wqT, qbf);
    k_kernel    <<<dim3((BB*NK)/256),    dim3(256), 0, stream>>>(xkv, wkT, kbf);
    v_kernel    <<<dim3(BB*32),          dim3(256), 0, stream>>>(xkv, wvoT, vobf);
    attn_kernel <<<dim3(BB*64),          dim3(256), 0, stream>>>(qbf, kbf, vobf, x, gamma, out);
}

// Round 3
// 115.168 us; speedup vs baseline: 6.8799x; 2.6281x over previous
//
#include <hip/hip_runtime.h>

#define BB 8
#define CC 256
#define NN 4096
#define DD 32
#define NK 1024

typedef unsigned short u16;
typedef unsigned int   u32;
typedef __attribute__((ext_vector_type(8))) short bf16x8;
typedef __attribute__((ext_vector_type(4))) float f32x4;

#define MFMA16 __builtin_amdgcn_mfma_f32_16x16x32_bf16

// workspace offsets (in floats) — total 2,793,472 f = 11.2 MB
#define OFF_XKVT 0u          // [B][NK][CC] bf16   1,048,576 f
#define OFF_WVO  1048576u    // [CC][CC] bf16         32,768 f
#define OFF_WQB  1081344u    // [DD][CC] bf16          4,096 f
#define OFF_WKB  1085440u    // [DD][CC] bf16          4,096 f
#define OFF_QBF  1089536u    // [B][NN][DD] bf16     524,288 f
#define OFF_KBF  1613824u    // [B][NK][DD] bf16     131,072 f
#define OFF_VOBF 1744896u    // [B][CC][NK] bf16   1,048,576 f
// xT_bf [B][NN][CC] bf16 (16 MB) lives in d_out (dead before attn writes out)

__device__ __forceinline__ u16 f2bf(float f) {
    u32 u = __float_as_uint(f);
    u += 0x7FFFu + ((u >> 16) & 1u);      // RNE
    return (u16)(u >> 16);
}

// ---- prep: x[B,C,64,64] -> xT_bf[B][N][C] (transpose) + xkvT_bf[B][Nk][C] --
// block tile: 64 c x 128 n (two image rows); grid = 8b x 4cb x 32hb = 1024
__launch_bounds__(256)
__global__ void prep_kernel(const float* __restrict__ x, u16* __restrict__ xT,
                            u16* __restrict__ xkvT) {
    __shared__ float xl[64 * 132];
    int blk = blockIdx.x;
    int b = blk & 7, rest = blk >> 3, cb = rest & 3, hb = rest >> 2;
    int c0 = cb * 64, n0 = hb * 128;
    int t = threadIdx.x;
    const float* xb = x + ((size_t)(b * CC + c0)) * NN + n0;
#pragma unroll
    for (int p = 0; p < 8; ++p) {
        int cr = p * 8 + (t >> 5);
        int ns = (t & 31) * 4;
        *(float4*)&xl[cr * 132 + ns] = *(const float4*)(xb + (size_t)cr * NN + ns);
    }
    __syncthreads();
    // transposed bf16 write: thread -> (n-local, c-half of 32)
    {
        int nl = t & 127, ch = t >> 7;
        u16* xp = xT + ((size_t)b * NN + n0 + nl) * CC + c0 + ch * 32;
        u32 wb[16];
#pragma unroll
        for (int j = 0; j < 16; ++j) {
            float a = xl[(ch * 32 + 2 * j) * 132 + nl];
            float c = xl[(ch * 32 + 2 * j + 1) * 132 + nl];
            wb[j] = (u32)f2bf(a) | ((u32)f2bf(c) << 16);
        }
#pragma unroll
        for (int j = 0; j < 4; ++j)
            *(uint4*)(xp + j * 8) = make_uint4(wb[4*j], wb[4*j+1], wb[4*j+2], wb[4*j+3]);
    }
    // pooled transposed bf16: m = hb*32 + wk, 8 c per thread
    {
        int wk = t & 31, co = t >> 5;
        u32 pw[4];
#pragma unroll
        for (int j = 0; j < 4; ++j) {
            int cl0 = co * 8 + 2 * j;
            float s0 = 0.25f * (xl[cl0*132 + 2*wk] + xl[cl0*132 + 2*wk + 1]
                              + xl[cl0*132 + 64 + 2*wk] + xl[cl0*132 + 65 + 2*wk]);
            int cl1 = cl0 + 1;
            float s1 = 0.25f * (xl[cl1*132 + 2*wk] + xl[cl1*132 + 2*wk + 1]
                              + xl[cl1*132 + 64 + 2*wk] + xl[cl1*132 + 65 + 2*wk]);
            pw[j] = (u32)f2bf(s0) | ((u32)f2bf(s1) << 16);
        }
        u16* kp = xkvT + ((size_t)b * NK + hb * 32 + wk) * CC + c0 + co * 8;
        *(uint4*)kp = make_uint4(pw[0], pw[1], pw[2], pw[3]);
    }
}

// ---- weight prep: wvo_bf[o][c] = (wo@wv)[o][c]; wq*QS, wk -> bf16 [d][c] ---
__global__ void wprep_kernel(const float* __restrict__ wq, const float* __restrict__ wk,
                             const float* __restrict__ wv, const float* __restrict__ wo,
                             u16* __restrict__ wqb, u16* __restrict__ wkb,
                             u16* __restrict__ wvob) {
    int o = blockIdx.x, c = threadIdx.x;
    float acc = 0.f;
#pragma unroll 8
    for (int j = 0; j < CC; ++j)
        acc += wo[o * CC + j] * wv[j * CC + c];
    wvob[o * CC + c] = f2bf(acc);
    int id = blockIdx.x * 256 + threadIdx.x;
    if (id < DD * CC) {
        const float QS = 0.17677669529663687f * 1.4426950408889634f; // 1/sqrt(32)*log2e
        wqb[id] = f2bf(wq[id] * QS);
        wkb[id] = f2bf(wk[id]);
    }
}

// ---- q & k projections (MFMA): out[n][d] = sum_c A[n][c] * W[d][c] --------
// blocks [0,256): q (A=xT, 128 n per block); [256,320): k (A=xkvT)
__launch_bounds__(256)
__global__ void qk_kernel(const u16* __restrict__ xT, const u16* __restrict__ xkvT,
                          const u16* __restrict__ wqb, const u16* __restrict__ wkb,
                          u16* __restrict__ qbf, u16* __restrict__ kbf) {
    int blk = blockIdx.x;
    const u16 *A, *Bw; u16* outp;
    if (blk < 256) {
        int b = blk & 7, rb = blk >> 3;
        A = xT + ((size_t)b * NN + rb * 128) * CC;
        Bw = wqb;
        outp = qbf + ((size_t)b * NN + rb * 128) * DD;
    } else {
        int k2 = blk - 256;
        int b = k2 & 7, rb = k2 >> 3;
        A = xkvT + ((size_t)b * NK + rb * 128) * CC;
        Bw = wkb;
        outp = kbf + ((size_t)b * NK + rb * 128) * DD;
    }
    int t = threadIdx.x, w = t >> 6, l = t & 63, l15 = l & 15, lg = l >> 4;
    const u16* Aw = A + (size_t)(w * 32) * CC;
    f32x4 acc[2][2];
    const f32x4 fz = {0.f, 0.f, 0.f, 0.f};
    acc[0][0] = fz; acc[0][1] = fz; acc[1][0] = fz; acc[1][1] = fz;
#pragma unroll
    for (int ks = 0; ks < 8; ++ks) {
        int k0 = ks * 32 + lg * 8;
        bf16x8 a0 = *(const bf16x8*)(Aw + (size_t)l15 * CC + k0);
        bf16x8 a1 = *(const bf16x8*)(Aw + (size_t)(16 + l15) * CC + k0);
        bf16x8 b0 = *(const bf16x8*)(Bw + (size_t)l15 * CC + k0);
        bf16x8 b1 = *(const bf16x8*)(Bw + (size_t)(16 + l15) * CC + k0);
        acc[0][0] = MFMA16(a0, b0, acc[0][0], 0, 0, 0);
        acc[0][1] = MFMA16(a0, b1, acc[0][1], 0, 0, 0);
        acc[1][0] = MFMA16(a1, b0, acc[1][0], 0, 0, 0);
        acc[1][1] = MFMA16(a1, b1, acc[1][1], 0, 0, 0);
    }
    u16* op = outp + (size_t)(w * 32) * DD;
#pragma unroll
    for (int i = 0; i < 2; ++i)
#pragma unroll
        for (int j = 0; j < 2; ++j)
#pragma unroll
            for (int r2 = 0; r2 < 4; ++r2)
                op[(size_t)(i * 16 + lg * 4 + r2) * DD + j * 16 + l15] = f2bf(acc[i][j][r2]);
}

// ---- vo projection (MFMA): vo[o][m] = sum_c wvo[o][c] * xkvT[m][c] ---------
// block: 64 o x 128 m (4 waves of 32o x 64m); grid = 8 x 4 x 8 = 256
__launch_bounds__(256)
__global__ void vo_kernel(const u16* __restrict__ xkvT, const u16* __restrict__ wvob,
                          u16* __restrict__ vobf) {
    int blk = blockIdx.x;
    int b = blk & 7, r = blk >> 3, ob = r & 3, mb = r >> 2;
    int t = threadIdx.x, w = t >> 6, l = t & 63, l15 = l & 15, lg = l >> 4;
    int o0 = ob * 64 + (w & 1) * 32;
    int m0 = mb * 128 + (w >> 1) * 64;
    const u16* ab = wvob + (size_t)o0 * CC;
    const u16* bb = xkvT + ((size_t)b * NK + m0) * CC;
    f32x4 acc[2][4];
    const f32x4 fz = {0.f, 0.f, 0.f, 0.f};
#pragma unroll
    for (int i = 0; i < 2; ++i)
#pragma unroll
        for (int j = 0; j < 4; ++j) acc[i][j] = fz;
#pragma unroll
    for (int ks = 0; ks < 8; ++ks) {
        int k0 = ks * 32 + lg * 8;
        bf16x8 a0 = *(const bf16x8*)(ab + (size_t)l15 * CC + k0);
        bf16x8 a1 = *(const bf16x8*)(ab + (size_t)(16 + l15) * CC + k0);
        bf16x8 bv0 = *(const bf16x8*)(bb + (size_t)(l15) * CC + k0);
        bf16x8 bv1 = *(const bf16x8*)(bb + (size_t)(16 + l15) * CC + k0);
        bf16x8 bv2 = *(const bf16x8*)(bb + (size_t)(32 + l15) * CC + k0);
        bf16x8 bv3 = *(const bf16x8*)(bb + (size_t)(48 + l15) * CC + k0);
        acc[0][0] = MFMA16(a0, bv0, acc[0][0], 0, 0, 0);
        acc[0][1] = MFMA16(a0, bv1, acc[0][1], 0, 0, 0);
        acc[0][2] = MFMA16(a0, bv2, acc[0][2], 0, 0, 0);
        acc[0][3] = MFMA16(a0, bv3, acc[0][3], 0, 0, 0);
        acc[1][0] = MFMA16(a1, bv0, acc[1][0], 0, 0, 0);
        acc[1][1] = MFMA16(a1, bv1, acc[1][1], 0, 0, 0);
        acc[1][2] = MFMA16(a1, bv2, acc[1][2], 0, 0, 0);
        acc[1][3] = MFMA16(a1, bv3, acc[1][3], 0, 0, 0);
    }
    u16* vp = vobf + ((size_t)b * CC + o0) * NK + m0;
#pragma unroll
    for (int i = 0; i < 2; ++i)
#pragma unroll
        for (int j = 0; j < 4; ++j)
#pragma unroll
            for (int r2 = 0; r2 < 4; ++r2)
                vp[(size_t)(i * 16 + lg * 4 + r2) * NK + j * 16 + l15] = f2bf(acc[i][j][r2]);
}

// ---------------- fused flash attention (MFMA) + epilogue -------------------
__launch_bounds__(256)
__global__ void attn_kernel(const u16* __restrict__ qbf, const u16* __restrict__ kbf,
                            const u16* __restrict__ vobf, const float* __restrict__ x,
                            const float* __restrict__ gamma, float* __restrict__ out) {
    __shared__ __align__(16) u16  vo_lds[2][256 * 40];
    __shared__ __align__(16) u16  p_lds[4][16 * 40];
    __shared__ __align__(16) float rs_lds[4][16];

    const int t  = threadIdx.x;
    const int w  = t >> 6, l = t & 63;
    const int l15 = l & 15, lg = l >> 4;
    const int b  = blockIdx.x & 7;
    const int n0 = (blockIdx.x >> 3) << 6;

    const u16* qb = qbf  + (size_t)b * NN * DD;
    const u16* kb = kbf  + (size_t)b * NK * DD;
    const u16* vb = vobf + (size_t)b * CC * NK;

    bf16x8 qf = *(const bf16x8*)(qb + (size_t)(n0 + w * 16 + l15) * DD + lg * 8);

    f32x4 acc[16];
    const f32x4 fzero = {0.f, 0.f, 0.f, 0.f};
#pragma unroll
    for (int i = 0; i < 16; ++i) acc[i] = fzero;
    float rs = 0.f;

    const int srow = t >> 2;
    const int sq   = t & 3;
    uint4 sreg[4];

#pragma unroll
    for (int j = 0; j < 4; ++j)
        sreg[j] = *(const uint4*)(vb + (size_t)(srow + j * 64) * NK + sq * 8);
#pragma unroll
    for (int j = 0; j < 4; ++j)
        *(uint4*)&vo_lds[0][(srow + j * 64) * 40 + sq * 8] = sreg[j];
    __syncthreads();

    for (int i = 0; i < 32; ++i) {
        const int buf = i & 1;
        const int mt  = i * 32;
        if (i < 31) {
#pragma unroll
            for (int j = 0; j < 4; ++j)
                sreg[j] = *(const uint4*)(vb + (size_t)(srow + j * 64) * NK + (mt + 32) + sq * 8);
        }
        bf16x8 kf0 = *(const bf16x8*)(kb + (size_t)(mt + l15) * DD + lg * 8);
        bf16x8 kf1 = *(const bf16x8*)(kb + (size_t)(mt + 16 + l15) * DD + lg * 8);
        f32x4 c0 = MFMA16(kf0, qf, fzero, 0, 0, 0);
        f32x4 c1 = MFMA16(kf1, qf, fzero, 0, 0, 0);
        float e0 = __builtin_amdgcn_exp2f(c0[0]);
        float e1 = __builtin_amdgcn_exp2f(c0[1]);
        float e2 = __builtin_amdgcn_exp2f(c0[2]);
        float e3 = __builtin_amdgcn_exp2f(c0[3]);
        float e4 = __builtin_amdgcn_exp2f(c1[0]);
        float e5 = __builtin_amdgcn_exp2f(c1[1]);
        float e6 = __builtin_amdgcn_exp2f(c1[2]);
        float e7 = __builtin_amdgcn_exp2f(c1[3]);
        rs += (e0 + e1 + e2 + e3) + (e4 + e5 + e6 + e7);
        uint2 pw0, pw1;
        pw0.x = (u32)f2bf(e0) | ((u32)f2bf(e1) << 16);
        pw0.y = (u32)f2bf(e2) | ((u32)f2bf(e3) << 16);
        pw1.x = (u32)f2bf(e4) | ((u32)f2bf(e5) << 16);
        pw1.y = (u32)f2bf(e6) | ((u32)f2bf(e7) << 16);
        u16* pw = &p_lds[w][l15 * 40 + lg * 4];
        *(uint2*)pw        = pw0;
        *(uint2*)(pw + 16) = pw1;
        bf16x8 pa = *(const bf16x8*)&p_lds[w][l15 * 40 + lg * 8];
#pragma unroll
        for (int ot = 0; ot < 16; ++ot) {
            bf16x8 bfr = *(const bf16x8*)&vo_lds[buf][(ot * 16 + l15) * 40 + lg * 8];
            acc[ot] = MFMA16(pa, bfr, acc[ot], 0, 0, 0);
        }
        if (i < 31) {
#pragma unroll
            for (int j = 0; j < 4; ++j)
                *(uint4*)&vo_lds[buf ^ 1][(srow + j * 64) * 40 + sq * 8] = sreg[j];
            __syncthreads();
        }
    }

    rs += __shfl_xor(rs, 16);
    rs += __shfl_xor(rs, 32);
    if (l < 16) rs_lds[w][l] = rs;
    float4 rv = *(const float4*)&rs_lds[w][lg * 4];
    float g = gamma[0];
    float fa0 = g / rv.x, fa1 = g / rv.y, fa2 = g / rv.z, fa3 = g / rv.w;

    const size_t nb = (size_t)n0 + w * 16 + lg * 4;
#pragma unroll
    for (int ot = 0; ot < 16; ++ot) {
        size_t base = ((size_t)(b * CC + ot * 16 + l15)) * NN + nb;
        float4 xv = *(const float4*)(x + base);
        float4 ov;
        ov.x = xv.x + acc[ot][0] * fa0;
        ov.y = xv.y + acc[ot][1] * fa1;
        ov.z = xv.z + acc[ot][2] * fa2;
        ov.w = xv.w + acc[ot][3] * fa3;
        *(float4*)(out + base) = ov;
    }
}

extern "C" void kernel_launch(void* const* d_in, const int* in_sizes, int n_in,
                              void* d_out, int out_size, void* d_ws, size_t ws_size,
                              hipStream_t stream) {
    const float* x     = (const float*)d_in[0];
    const float* wq    = (const float*)d_in[1];
    const float* wk    = (const float*)d_in[2];
    const float* wv    = (const float*)d_in[3];
    const float* wo    = (const float*)d_in[4];
    const float* gamma = (const float*)d_in[5];
    float* out = (float*)d_out;
    float* ws  = (float*)d_ws;

    u16* xkvT = (u16*)(ws + OFF_XKVT);
    u16* wvob = (u16*)(ws + OFF_WVO);
    u16* wqb  = (u16*)(ws + OFF_WQB);
    u16* wkb  = (u16*)(ws + OFF_WKB);
    u16* qbf  = (u16*)(ws + OFF_QBF);
    u16* kbf  = (u16*)(ws + OFF_KBF);
    u16* vobf = (u16*)(ws + OFF_VOBF);
    u16* xT   = (u16*)d_out;     // 16 MB scratch in d_out; dead before attn writes

    prep_kernel <<<dim3(1024), dim3(256), 0, stream>>>(x, xT, xkvT);
    wprep_kernel<<<dim3(256),  dim3(256), 0, stream>>>(wq, wk, wv, wo, wqb, wkb, wvob);
    qk_kernel   <<<dim3(320),  dim3(256), 0, stream>>>(xT, xkvT, wqb, wkb, qbf, kbf);
    vo_kernel   <<<dim3(256),  dim3(256), 0, stream>>>(xkvT, wvob, vobf);
    attn_kernel <<<dim3(512),  dim3(256), 0, stream>>>(qbf, kbf, vobf, x, gamma, out);
}

// Round 4
// 92.756 us; speedup vs baseline: 8.5423x; 1.2416x over previous
//
#include <hip/hip_runtime.h>

#define BB 8
#define CC 256
#define NN 4096
#define DD 32
#define NK 1024

typedef unsigned short u16;
typedef unsigned int   u32;
typedef __attribute__((ext_vector_type(8))) short bf16x8;
typedef __attribute__((ext_vector_type(4))) float f32x4;

#define MFMA16 __builtin_amdgcn_mfma_f32_16x16x32_bf16

// workspace offsets (in floats) — total 2,793,472 f = 11.2 MB
#define OFF_XKVT 0u          // [B][NK][CC] bf16   1,048,576 f
#define OFF_WVO  1048576u    // [CC][CC] bf16         32,768 f
#define OFF_WQB  1081344u    // [DD][CC] bf16          4,096 f
#define OFF_WKB  1085440u    // [DD][CC] bf16          4,096 f
#define OFF_QBF  1089536u    // [B][NN][DD] bf16     524,288 f
#define OFF_KBF  1613824u    // [B][NK][DD] bf16     131,072 f
#define OFF_VOBF 1744896u    // [B][CC][NK] bf16   1,048,576 f
// xT_bf [B][NN][CC] bf16 (16 MB) lives in d_out (dead before attn writes out)

__device__ __forceinline__ u16 f2bf(float f) {
    u32 u = __float_as_uint(f);
    u += 0x7FFFu + ((u >> 16) & 1u);      // RNE
    return (u16)(u >> 16);
}

__device__ __forceinline__ u32 cvt_pk_bf16(float lo, float hi) {
    u32 r;
    asm("v_cvt_pk_bf16_f32 %0, %1, %2" : "=v"(r) : "v"(lo), "v"(hi));
    return r;
}

// ---- prep: x[B,C,64,64] -> xT_bf[B][N][C] (transpose) + xkvT_bf[B][Nk][C] --
__launch_bounds__(256)
__global__ void prep_kernel(const float* __restrict__ x, u16* __restrict__ xT,
                            u16* __restrict__ xkvT) {
    __shared__ float xl[64 * 132];
    int blk = blockIdx.x;
    int b = blk & 7, rest = blk >> 3, cb = rest & 3, hb = rest >> 2;
    int c0 = cb * 64, n0 = hb * 128;
    int t = threadIdx.x;
    const float* xb = x + ((size_t)(b * CC + c0)) * NN + n0;
#pragma unroll
    for (int p = 0; p < 8; ++p) {
        int cr = p * 8 + (t >> 5);
        int ns = (t & 31) * 4;
        *(float4*)&xl[cr * 132 + ns] = *(const float4*)(xb + (size_t)cr * NN + ns);
    }
    __syncthreads();
    {
        int nl = t & 127, ch = t >> 7;
        u16* xp = xT + ((size_t)b * NN + n0 + nl) * CC + c0 + ch * 32;
        u32 wb[16];
#pragma unroll
        for (int j = 0; j < 16; ++j) {
            float a = xl[(ch * 32 + 2 * j) * 132 + nl];
            float c = xl[(ch * 32 + 2 * j + 1) * 132 + nl];
            wb[j] = (u32)f2bf(a) | ((u32)f2bf(c) << 16);
        }
#pragma unroll
        for (int j = 0; j < 4; ++j)
            *(uint4*)(xp + j * 8) = make_uint4(wb[4*j], wb[4*j+1], wb[4*j+2], wb[4*j+3]);
    }
    {
        int wk = t & 31, co = t >> 5;
        u32 pw[4];
#pragma unroll
        for (int j = 0; j < 4; ++j) {
            int cl0 = co * 8 + 2 * j;
            float s0 = 0.25f * (xl[cl0*132 + 2*wk] + xl[cl0*132 + 2*wk + 1]
                              + xl[cl0*132 + 64 + 2*wk] + xl[cl0*132 + 65 + 2*wk]);
            int cl1 = cl0 + 1;
            float s1 = 0.25f * (xl[cl1*132 + 2*wk] + xl[cl1*132 + 2*wk + 1]
                              + xl[cl1*132 + 64 + 2*wk] + xl[cl1*132 + 65 + 2*wk]);
            pw[j] = (u32)f2bf(s0) | ((u32)f2bf(s1) << 16);
        }
        u16* kp = xkvT + ((size_t)b * NK + hb * 32 + wk) * CC + c0 + co * 8;
        *(uint4*)kp = make_uint4(pw[0], pw[1], pw[2], pw[3]);
    }
}

// ---- weight prep -----------------------------------------------------------
__global__ void wprep_kernel(const float* __restrict__ wq, const float* __restrict__ wk,
                             const float* __restrict__ wv, const float* __restrict__ wo,
                             u16* __restrict__ wqb, u16* __restrict__ wkb,
                             u16* __restrict__ wvob) {
    int o = blockIdx.x, c = threadIdx.x;
    float acc = 0.f;
#pragma unroll 8
    for (int j = 0; j < CC; ++j)
        acc += wo[o * CC + j] * wv[j * CC + c];
    wvob[o * CC + c] = f2bf(acc);
    int id = blockIdx.x * 256 + threadIdx.x;
    if (id < DD * CC) {
        const float QS = 0.17677669529663687f * 1.4426950408889634f; // 1/sqrt(32)*log2e
        wqb[id] = f2bf(wq[id] * QS);
        wkb[id] = f2bf(wk[id]);
    }
}

// ---- q & k projections (MFMA) ----------------------------------------------
__launch_bounds__(256)
__global__ void qk_kernel(const u16* __restrict__ xT, const u16* __restrict__ xkvT,
                          const u16* __restrict__ wqb, const u16* __restrict__ wkb,
                          u16* __restrict__ qbf, u16* __restrict__ kbf) {
    int blk = blockIdx.x;
    const u16 *A, *Bw; u16* outp;
    if (blk < 256) {
        int b = blk & 7, rb = blk >> 3;
        A = xT + ((size_t)b * NN + rb * 128) * CC;
        Bw = wqb;
        outp = qbf + ((size_t)b * NN + rb * 128) * DD;
    } else {
        int k2 = blk - 256;
        int b = k2 & 7, rb = k2 >> 3;
        A = xkvT + ((size_t)b * NK + rb * 128) * CC;
        Bw = wkb;
        outp = kbf + ((size_t)b * NK + rb * 128) * DD;
    }
    int t = threadIdx.x, w = t >> 6, l = t & 63, l15 = l & 15, lg = l >> 4;
    const u16* Aw = A + (size_t)(w * 32) * CC;
    f32x4 acc[2][2];
    const f32x4 fz = {0.f, 0.f, 0.f, 0.f};
    acc[0][0] = fz; acc[0][1] = fz; acc[1][0] = fz; acc[1][1] = fz;
#pragma unroll
    for (int ks = 0; ks < 8; ++ks) {
        int k0 = ks * 32 + lg * 8;
        bf16x8 a0 = *(const bf16x8*)(Aw + (size_t)l15 * CC + k0);
        bf16x8 a1 = *(const bf16x8*)(Aw + (size_t)(16 + l15) * CC + k0);
        bf16x8 b0 = *(const bf16x8*)(Bw + (size_t)l15 * CC + k0);
        bf16x8 b1 = *(const bf16x8*)(Bw + (size_t)(16 + l15) * CC + k0);
        acc[0][0] = MFMA16(a0, b0, acc[0][0], 0, 0, 0);
        acc[0][1] = MFMA16(a0, b1, acc[0][1], 0, 0, 0);
        acc[1][0] = MFMA16(a1, b0, acc[1][0], 0, 0, 0);
        acc[1][1] = MFMA16(a1, b1, acc[1][1], 0, 0, 0);
    }
    u16* op = outp + (size_t)(w * 32) * DD;
#pragma unroll
    for (int i = 0; i < 2; ++i)
#pragma unroll
        for (int j = 0; j < 2; ++j)
#pragma unroll
            for (int r2 = 0; r2 < 4; ++r2)
                op[(size_t)(i * 16 + lg * 4 + r2) * DD + j * 16 + l15] = f2bf(acc[i][j][r2]);
}

// ---- vo projection (MFMA) ---------------------------------------------------
__launch_bounds__(256)
__global__ void vo_kernel(const u16* __restrict__ xkvT, const u16* __restrict__ wvob,
                          u16* __restrict__ vobf) {
    int blk = blockIdx.x;
    int b = blk & 7, r = blk >> 3, ob = r & 3, mb = r >> 2;
    int t = threadIdx.x, w = t >> 6, l = t & 63, l15 = l & 15, lg = l >> 4;
    int o0 = ob * 64 + (w & 1) * 32;
    int m0 = mb * 128 + (w >> 1) * 64;
    const u16* ab = wvob + (size_t)o0 * CC;
    const u16* bb = xkvT + ((size_t)b * NK + m0) * CC;
    f32x4 acc[2][4];
    const f32x4 fz = {0.f, 0.f, 0.f, 0.f};
#pragma unroll
    for (int i = 0; i < 2; ++i)
#pragma unroll
        for (int j = 0; j < 4; ++j) acc[i][j] = fz;
#pragma unroll
    for (int ks = 0; ks < 8; ++ks) {
        int k0 = ks * 32 + lg * 8;
        bf16x8 a0 = *(const bf16x8*)(ab + (size_t)l15 * CC + k0);
        bf16x8 a1 = *(const bf16x8*)(ab + (size_t)(16 + l15) * CC + k0);
        bf16x8 bv0 = *(const bf16x8*)(bb + (size_t)(l15) * CC + k0);
        bf16x8 bv1 = *(const bf16x8*)(bb + (size_t)(16 + l15) * CC + k0);
        bf16x8 bv2 = *(const bf16x8*)(bb + (size_t)(32 + l15) * CC + k0);
        bf16x8 bv3 = *(const bf16x8*)(bb + (size_t)(48 + l15) * CC + k0);
        acc[0][0] = MFMA16(a0, bv0, acc[0][0], 0, 0, 0);
        acc[0][1] = MFMA16(a0, bv1, acc[0][1], 0, 0, 0);
        acc[0][2] = MFMA16(a0, bv2, acc[0][2], 0, 0, 0);
        acc[0][3] = MFMA16(a0, bv3, acc[0][3], 0, 0, 0);
        acc[1][0] = MFMA16(a1, bv0, acc[1][0], 0, 0, 0);
        acc[1][1] = MFMA16(a1, bv1, acc[1][1], 0, 0, 0);
        acc[1][2] = MFMA16(a1, bv2, acc[1][2], 0, 0, 0);
        acc[1][3] = MFMA16(a1, bv3, acc[1][3], 0, 0, 0);
    }
    u16* vp = vobf + ((size_t)b * CC + o0) * NK + m0;
#pragma unroll
    for (int i = 0; i < 2; ++i)
#pragma unroll
        for (int j = 0; j < 4; ++j)
#pragma unroll
            for (int r2 = 0; r2 < 4; ++r2)
                vp[(size_t)(i * 16 + lg * 4 + r2) * NK + j * 16 + l15] = f2bf(acc[i][j][r2]);
}

// ---------------- fused flash attention (MFMA) + epilogue -------------------
// block: 4 waves; 64 q-rows/block. Wave w: QK for n-tile w, PV for o-slice w*64.
// P shared via dbuf LDS (1 barrier/iter); VO read directly from L2 (XCD-pinned).
__launch_bounds__(256)
__global__ void attn_kernel(const u16* __restrict__ qbf, const u16* __restrict__ kbf,
                            const u16* __restrict__ vobf, const float* __restrict__ x,
                            const float* __restrict__ gamma, float* __restrict__ out) {
    __shared__ __align__(16) u16   p_lds[2][64 * 40];   // [n][32m] pad-40, dbuf (10 KB)
    __shared__ __align__(16) float rs_lds[64];

    const int t  = threadIdx.x;
    const int w  = t >> 6, l = t & 63;
    const int l15 = l & 15, lg = l >> 4;
    const int b  = blockIdx.x & 7;               // batch -> XCD pin
    const int n0 = (blockIdx.x >> 3) << 6;       // 64-row tile
    const int o0 = w * 64;                       // wave's o-slice

    const u16* qb = qbf  + (size_t)b * NN * DD;
    const u16* kb = kbf  + (size_t)b * NK * DD;
    const u16* vb = vobf + (size_t)b * CC * NK;

    // Q fragment (B operand): col n = n0 + w*16 + l15, k = lg*8..+7
    bf16x8 qf = *(const bf16x8*)(qb + (size_t)(n0 + w * 16 + l15) * DD + lg * 8);

    // lane-base pointers
    const u16* kfp = kb + (size_t)l15 * DD + lg * 8;          // + m*DD
    const u16* vbl = vb + (size_t)(o0 + l15) * NK + lg * 8;   // + of*16*NK + mt
    u16*       pwp = &p_lds[0][(w * 16 + l15) * 40 + lg * 4]; // + buf*2560 (u16)
    const u16* prp = &p_lds[0][l15 * 40 + lg * 8];            // + buf*2560 + j*640

    f32x4 acc[4][4];
    const f32x4 fz = {0.f, 0.f, 0.f, 0.f};
#pragma unroll
    for (int j = 0; j < 4; ++j)
#pragma unroll
        for (int of = 0; of < 4; ++of) acc[j][of] = fz;
    float rs = 0.f;

    // software-pipelined K fragments
    bf16x8 kf0 = *(const bf16x8*)(kfp);
    bf16x8 kf1 = *(const bf16x8*)(kfp + 16 * DD);

#pragma unroll 2
    for (int i = 0; i < 32; ++i) {
        const int mt  = i * 32;
        const int buf = i & 1;
        // ---- VO B-fragment prefetch (L2) — consumed after the barrier -------
        bf16x8 vof[4];
#pragma unroll
        for (int of = 0; of < 4; ++of)
            vof[of] = *(const bf16x8*)(vbl + (size_t)(of * 16) * NK + mt);
        // ---- next-iter K prefetch -------------------------------------------
        bf16x8 kn0, kn1;
        if (i < 31) {
            kn0 = *(const bf16x8*)(kfp + (size_t)(mt + 32) * DD);
            kn1 = *(const bf16x8*)(kfp + (size_t)(mt + 48) * DD);
        }
        // ---- S^T tile: lane n = l15, m = mt + lg*4 + r (+16) ----------------
        f32x4 c0 = MFMA16(kf0, qf, fz, 0, 0, 0);
        f32x4 c1 = MFMA16(kf1, qf, fz, 0, 0, 0);
        float e0 = __builtin_amdgcn_exp2f(c0[0]);
        float e1 = __builtin_amdgcn_exp2f(c0[1]);
        float e2 = __builtin_amdgcn_exp2f(c0[2]);
        float e3 = __builtin_amdgcn_exp2f(c0[3]);
        float e4 = __builtin_amdgcn_exp2f(c1[0]);
        float e5 = __builtin_amdgcn_exp2f(c1[1]);
        float e6 = __builtin_amdgcn_exp2f(c1[2]);
        float e7 = __builtin_amdgcn_exp2f(c1[3]);
        rs += (e0 + e1 + e2 + e3) + (e4 + e5 + e6 + e7);
        uint2 pw0, pw1;
        pw0.x = cvt_pk_bf16(e0, e1);
        pw0.y = cvt_pk_bf16(e2, e3);
        pw1.x = cvt_pk_bf16(e4, e5);
        pw1.y = cvt_pk_bf16(e6, e7);
        u16* pw = pwp + buf * 2560;
        *(uint2*)pw        = pw0;   // m-local lg*4..+3
        *(uint2*)(pw + 16) = pw1;   // m-local 16+lg*4..+3
        __syncthreads();
        // ---- PV: 4 n-tiles x 4 o-frags --------------------------------------
        const u16* pr = prp + buf * 2560;
#pragma unroll
        for (int j = 0; j < 4; ++j) {
            bf16x8 pa = *(const bf16x8*)(pr + j * 640);
#pragma unroll
            for (int of = 0; of < 4; ++of)
                acc[j][of] = MFMA16(pa, vof[of], acc[j][of], 0, 0, 0);
        }
        kf0 = kn0; kf1 = kn1;
    }

    // ---- row sums: lane holds partial for n = w*16 + l15 --------------------
    rs += __shfl_xor(rs, 16);
    rs += __shfl_xor(rs, 32);
    if (l < 16) rs_lds[w * 16 + l] = rs;
    __syncthreads();

    float g = gamma[0];
#pragma unroll
    for (int j = 0; j < 4; ++j) {
        float4 rv = *(const float4*)&rs_lds[j * 16 + lg * 4];
        float fa0 = g / rv.x, fa1 = g / rv.y, fa2 = g / rv.z, fa3 = g / rv.w;
#pragma unroll
        for (int of = 0; of < 4; ++of) {
            size_t base = ((size_t)(b * CC + o0 + of * 16 + l15)) * NN
                        + n0 + j * 16 + lg * 4;
            float4 xv = *(const float4*)(x + base);
            float4 ov;
            ov.x = xv.x + acc[j][of][0] * fa0;
            ov.y = xv.y + acc[j][of][1] * fa1;
            ov.z = xv.z + acc[j][of][2] * fa2;
            ov.w = xv.w + acc[j][of][3] * fa3;
            *(float4*)(out + base) = ov;
        }
    }
}

extern "C" void kernel_launch(void* const* d_in, const int* in_sizes, int n_in,
                              void* d_out, int out_size, void* d_ws, size_t ws_size,
                              hipStream_t stream) {
    const float* x     = (const float*)d_in[0];
    const float* wq    = (const float*)d_in[1];
    const float* wk    = (const float*)d_in[2];
    const float* wv    = (const float*)d_in[3];
    const float* wo    = (const float*)d_in[4];
    const float* gamma = (const float*)d_in[5];
    float* out = (float*)d_out;
    float* ws  = (float*)d_ws;

    u16* xkvT = (u16*)(ws + OFF_XKVT);
    u16* wvob = (u16*)(ws + OFF_WVO);
    u16* wqb  = (u16*)(ws + OFF_WQB);
    u16* wkb  = (u16*)(ws + OFF_WKB);
    u16* qbf  = (u16*)(ws + OFF_QBF);
    u16* kbf  = (u16*)(ws + OFF_KBF);
    u16* vobf = (u16*)(ws + OFF_VOBF);
    u16* xT   = (u16*)d_out;     // 16 MB scratch in d_out; dead before attn writes

    prep_kernel <<<dim3(1024), dim3(256), 0, stream>>>(x, xT, xkvT);
    wprep_kernel<<<dim3(256),  dim3(256), 0, stream>>>(wq, wk, wv, wo, wqb, wkb, wvob);
    qk_kernel   <<<dim3(320),  dim3(256), 0, stream>>>(xT, xkvT, wqb, wkb, qbf, kbf);
    vo_kernel   <<<dim3(256),  dim3(256), 0, stream>>>(xkvT, wvob, vobf);
    attn_kernel <<<dim3(512),  dim3(256), 0, stream>>>(qbf, kbf, vobf, x, gamma, out);
}